// Round 11
// baseline (1044.973 us; speedup 1.0000x reference)
//
#include <hip/hip_runtime.h>
#include <hip/hip_bf16.h>
#include <math.h>

// Problem constants
#define B_SZ 1024
#define T_SZ 512
#define CTX_N 23
#define D 320
#define L_LAYERS 5
#define H 8
#define FF 1280
#define NM1 49      // NMODES + 1
#define S 24        // CTX + 1
#define DH 40       // D / H
#define M_ROWS (B_SZ * S)   // 24576

typedef unsigned short ushort_t;
typedef __attribute__((ext_vector_type(8))) short bfrag8;          // 8 bf16
typedef __attribute__((ext_vector_type(8))) unsigned short us8v;   // 8 bf16
typedef __attribute__((ext_vector_type(4))) float facc4;           // 4 fp32

__device__ __forceinline__ float wave_sum(float v) {
#pragma unroll
  for (int off = 32; off > 0; off >>= 1) v += __shfl_xor(v, off, 64);
  return v;
}

// tanh-form gelu (max |err| ~3e-4 << bf16 quantum, safe at +-inf)
__device__ __forceinline__ float gelu_fast(float x) {
  float t = __builtin_amdgcn_exp2f(x * (2.30211416f + 0.10294404f * x * x));
  return x - x * __builtin_amdgcn_rcpf(t + 1.0f);
}

__device__ __forceinline__ ushort_t f2b(float x) {
  __hip_bfloat16 h = __float2bfloat16(x);
  return *reinterpret_cast<ushort_t*>(&h);
}

__device__ __forceinline__ float b2f(ushort_t u) {
  __hip_bfloat16 h = *reinterpret_cast<__hip_bfloat16*>(&u);
  return __bfloat162float(h);
}

#define GLOAD_LDS16(g, l)                                     \
  __builtin_amdgcn_global_load_lds(                           \
      (const __attribute__((address_space(1))) void*)(g),     \
      (__attribute__((address_space(3))) void*)(l), 16, 0, 0)

// ---------------- all-weights f32 -> bf16 (dst regions contiguous) -----------
__global__ __launch_bounds__(256) void conv_all(
    const float* __restrict__ w_in, const float* __restrict__ w_out,
    const float* __restrict__ w1, const float* __restrict__ w2,
    const float* __restrict__ wh1, ushort_t* __restrict__ dst) {
  int i = blockIdx.x * 256 + threadIdx.x;
  const float* src;
  int off;
  if (i < 384000)       { src = w_in;  off = i; }
  else if (i < 512000)  { src = w_out; off = i - 384000; }
  else if (i < 1024000) { src = w1;    off = i - 512000; }
  else if (i < 1536000) { src = w2;    off = i - 1024000; }
  else                  { src = wh1;   off = i - 1536000; }
  float4 v = ((const float4*)src)[off];
  ushort4 o;
  o.x = f2b(v.x); o.y = f2b(v.y); o.z = f2b(v.z); o.w = f2b(v.w);
  ((ushort4*)dst)[i] = o;
}

// ---------------- embed + layer-0 LN stats: one wave per row -----------------
__global__ __launch_bounds__(256) void embed_stats(
    const float* __restrict__ ctx, const float* __restrict__ W_e,
    const float* __restrict__ b_e, const float* __restrict__ cls,
    float* __restrict__ x, float* __restrict__ stats) {
  int wvi = threadIdx.x >> 6;
  int lane = threadIdx.x & 63;
  int row = blockIdx.x * 4 + wvi;
  int b = row / S, s = row % S;
  float c = (s == 0) ? 0.f : ctx[b * CTX_N + (s - 1)];
  float* xr = x + (size_t)row * D;
  float vs = 0.f, vq = 0.f;
#pragma unroll
  for (int i = 0; i < 5; i++) {
    int d = lane + 64 * i;
    float v = (s == 0) ? cls[d] : c * W_e[d] + b_e[d];
    xr[d] = v;
    vs += v;
    vq += v * v;
  }
  vs = wave_sum(vs);
  vq = wave_sum(vq);
  if (lane == 0) {
    stats[2 * row] = vs;
    stats[2 * row + 1] = vq;
  }
}

// ---------------- layernorm (head only): fp32 in, bf16 out -------------------
__global__ __launch_bounds__(256) void ln_kernel(
    const float* __restrict__ X, const float* __restrict__ w,
    const float* __restrict__ b, ushort_t* __restrict__ Y,
    int inStride, int outStride) {
  int wv = threadIdx.x >> 6;
  int lane = threadIdx.x & 63;
  int row = blockIdx.x * 4 + wv;
  const float* xr = X + (size_t)row * inStride;
  float v[5];
#pragma unroll
  for (int i = 0; i < 5; i++) v[i] = xr[lane + 64 * i];
  float s = v[0] + v[1] + v[2] + v[3] + v[4];
  s = wave_sum(s);
  float m = s * (1.0f / (float)D);
  float sq = 0.f;
#pragma unroll
  for (int i = 0; i < 5; i++) { float d0 = v[i] - m; sq += d0 * d0; }
  sq = wave_sum(sq);
  float inv = 1.0f / sqrtf(sq * (1.0f / (float)D) + 1e-5f);
  ushort_t* yr = Y + (size_t)row * outStride;
#pragma unroll
  for (int i = 0; i < 5; i++) {
    int d = lane + 64 * i;
    yr[d] = f2b((v[i] - m) * inv * w[d] + b[d]);
  }
}

// ---------------- bf16 MFMA GEMM (R5 core), BM=64/BN=160, 2-barrier ----------
// EPI: 2=bias+residual->f32, 3=bias+gelu->f32, 6=bias+residual->f32 + LN
// stats (sum,sumsq per output row via shuffle-reduce + atomicAdd).
template <int EPI, int BM_, int NT>
__global__ __launch_bounds__(256, 3) void gemm_mfma(
    const ushort_t* __restrict__ A, const ushort_t* __restrict__ W,
    const float* __restrict__ bias, const float* __restrict__ R,
    float* __restrict__ C, ushort_t* __restrict__ Cb,
    float* __restrict__ stats, int M, int N, int K) {
  constexpr int BK = 64;
  constexpr int BN = 32 * NT;
  constexpr int MT = BM_ / 32;
  constexpr int AR = BM_ / 32;
  constexpr int WR = BN / 32;
  __shared__ __align__(16) ushort_t As[BM_ * BK];
  __shared__ __align__(16) ushort_t Ws[BN * BK];

  int tid = threadIdx.x;
  int lane = tid & 63;
  int wv = tid >> 6;
  int wvM = wv & 1, wvN = wv >> 1;
  int laneM = lane & 15;
  int kgrp = lane >> 4;
  int sA = laneM & 7;
  int m0 = blockIdx.x * BM_;
  int n0 = blockIdx.y * BN;

  facc4 acc[MT][NT];
#pragma unroll
  for (int mt = 0; mt < MT; mt++)
#pragma unroll
    for (int nt = 0; nt < NT; nt++) acc[mt][nt] = (facc4){0.f, 0.f, 0.f, 0.f};

  int srow = tid >> 3;
  int jg = (tid & 7) ^ (srow & 7);
  const ushort_t* Ag = A + (size_t)(m0 + srow) * K + jg * 8;
  const ushort_t* Wg = W + (size_t)(n0 + srow) * K + jg * 8;

  for (int k0 = 0; k0 < K; k0 += BK) {
#pragma unroll
    for (int r = 0; r < AR; r++)
      GLOAD_LDS16(Ag + (size_t)r * 32 * K + k0, As + r * 2048 + tid * 8);
#pragma unroll
    for (int r = 0; r < WR; r++)
      GLOAD_LDS16(Wg + (size_t)r * 32 * K + k0, Ws + r * 2048 + tid * 8);
    __syncthreads();
#pragma unroll
    for (int kc = 0; kc < 2; kc++) {
      int jcol = ((kc * 4 + kgrp) ^ sA) * 8;
      bfrag8 af[MT];
#pragma unroll
      for (int mt = 0; mt < MT; mt++) {
        int row = wvM * (BM_ / 2) + mt * 16 + laneM;
        af[mt] = *(const bfrag8*)&As[row * 64 + jcol];
      }
      bfrag8 bf[NT];
#pragma unroll
      for (int nt = 0; nt < NT; nt++) {
        int nrow = wvN * (BN / 2) + nt * 16 + laneM;
        bf[nt] = *(const bfrag8*)&Ws[nrow * 64 + jcol];
      }
#pragma unroll
      for (int mt = 0; mt < MT; mt++)
#pragma unroll
        for (int nt = 0; nt < NT; nt++)
          acc[mt][nt] = __builtin_amdgcn_mfma_f32_16x16x32_bf16(
              bf[nt], af[mt], acc[mt][nt], 0, 0, 0);   // swapped: D[n][m]
    }
    __syncthreads();
  }

#pragma unroll
  for (int mt = 0; mt < MT; mt++) {
    int m = m0 + wvM * (BM_ / 2) + mt * 16 + laneM;
    float rs = 0.f, rq = 0.f;
#pragma unroll
    for (int nt = 0; nt < NT; nt++) {
      int n = n0 + wvN * (BN / 2) + nt * 16 + kgrp * 4;
      float4 bv = *(const float4*)(bias + n);
      facc4 a = acc[mt][nt];
      float v0 = a[0] + bv.x, v1 = a[1] + bv.y, v2 = a[2] + bv.z,
            v3 = a[3] + bv.w;
      size_t off = (size_t)m * N + n;
      if constexpr (EPI == 2 || EPI == 6) {
        float4 r = *(const float4*)(R + off);
        float4 o = {v0 + r.x, v1 + r.y, v2 + r.z, v3 + r.w};
        *(float4*)(C + off) = o;
        if constexpr (EPI == 6) {
          rs += o.x + o.y + o.z + o.w;
          rq += o.x * o.x + o.y * o.y + o.z * o.z + o.w * o.w;
        }
      } else if constexpr (EPI == 3) {
        float4 o = {gelu_fast(v0), gelu_fast(v1), gelu_fast(v2),
                    gelu_fast(v3)};
        *(float4*)(C + off) = o;
      }
    }
    if constexpr (EPI == 6) {
      rs += __shfl_xor(rs, 16, 64);
      rs += __shfl_xor(rs, 32, 64);
      rq += __shfl_xor(rq, 16, 64);
      rq += __shfl_xor(rq, 32, 64);
      if (kgrp == 0) {
        atomicAdd(stats + 2 * m, rs);
        atomicAdd(stats + 2 * m + 1, rq);
      }
    }
  }
}

// ---------------- fused-LN bf16 MFMA GEMM: A = LN(x) on the fly --------------
// A staged via VGPRs: load f32 x, apply (x*alpha+beta)*w+b, pack bf16,
// ds_write_b128 into the SAME swizzled LDS slots; W stays global_load_lds.
// EPI: 1=bias+gelu->bf16 (ffn1), 4=bias->bf16 (qkv). BM=64.
template <int EPI, int NT>
__global__ __launch_bounds__(256, 3) void gemm_ln(
    const float* __restrict__ Xf, const ushort_t* __restrict__ W,
    const float* __restrict__ lnw, const float* __restrict__ lnb,
    const float* __restrict__ stats, const float* __restrict__ bias,
    ushort_t* __restrict__ Cb, int M, int N, int K) {
  constexpr int BM_ = 64, BK = 64;
  constexpr int BN = 32 * NT;
  constexpr int MT = 2;
  constexpr int WR = BN / 32;
  __shared__ __align__(16) ushort_t As[BM_ * BK];
  __shared__ __align__(16) ushort_t Ws[BN * BK];

  int tid = threadIdx.x;
  int lane = tid & 63;
  int wv = tid >> 6;
  int wvM = wv & 1, wvN = wv >> 1;
  int laneM = lane & 15;
  int kgrp = lane >> 4;
  int sA = laneM & 7;
  int m0 = blockIdx.x * BM_;
  int n0 = blockIdx.y * BN;

  facc4 acc[MT][NT];
#pragma unroll
  for (int mt = 0; mt < MT; mt++)
#pragma unroll
    for (int nt = 0; nt < NT; nt++) acc[mt][nt] = (facc4){0.f, 0.f, 0.f, 0.f};

  int srow = tid >> 3;
  int jg = (tid & 7) ^ (srow & 7);
  const float* Xg = Xf + (size_t)(m0 + srow) * K + jg * 8;
  const ushort_t* Wg = W + (size_t)(n0 + srow) * K + jg * 8;

  // per-row LN coefficients (rows fixed across K-loop)
  float alpha[2], beta[2];
#pragma unroll
  for (int r = 0; r < 2; r++) {
    int row = m0 + srow + r * 32;
    float sm = stats[2 * row] * (1.0f / (float)D);
    float sq = stats[2 * row + 1] * (1.0f / (float)D);
    float rstd = rsqrtf(sq - sm * sm + 1e-5f);
    alpha[r] = rstd;
    beta[r] = -sm * rstd;
  }

  for (int k0 = 0; k0 < K; k0 += BK) {
    // W async stage first (latency overlaps A's VALU staging below)
#pragma unroll
    for (int r = 0; r < WR; r++)
      GLOAD_LDS16(Wg + (size_t)r * 32 * K + k0, Ws + r * 2048 + tid * 8);
    // LN coefs for this iter's 8 columns (shared by both rows)
    const float4* wp = (const float4*)(lnw + k0 + jg * 8);
    const float4* bp = (const float4*)(lnb + k0 + jg * 8);
    float4 w0 = wp[0], w1 = wp[1];
    float4 c0 = bp[0], c1 = bp[1];
#pragma unroll
    for (int r = 0; r < 2; r++) {
      const float4* xp = (const float4*)(Xg + (size_t)r * 32 * K + k0);
      float4 x0 = xp[0], x1 = xp[1];
      float al = alpha[r], be = beta[r];
      us8v u;
      u[0] = f2b(fmaf(fmaf(x0.x, al, be), w0.x, c0.x));
      u[1] = f2b(fmaf(fmaf(x0.y, al, be), w0.y, c0.y));
      u[2] = f2b(fmaf(fmaf(x0.z, al, be), w0.z, c0.z));
      u[3] = f2b(fmaf(fmaf(x0.w, al, be), w0.w, c0.w));
      u[4] = f2b(fmaf(fmaf(x1.x, al, be), w1.x, c1.x));
      u[5] = f2b(fmaf(fmaf(x1.y, al, be), w1.y, c1.y));
      u[6] = f2b(fmaf(fmaf(x1.z, al, be), w1.z, c1.z));
      u[7] = f2b(fmaf(fmaf(x1.w, al, be), w1.w, c1.w));
      *(us8v*)&As[r * 2048 + tid * 8] = u;
    }
    __syncthreads();
#pragma unroll
    for (int kc = 0; kc < 2; kc++) {
      int jcol = ((kc * 4 + kgrp) ^ sA) * 8;
      bfrag8 af[MT];
#pragma unroll
      for (int mt = 0; mt < MT; mt++) {
        int row = wvM * 32 + mt * 16 + laneM;
        af[mt] = *(const bfrag8*)&As[row * 64 + jcol];
      }
      bfrag8 bf[NT];
#pragma unroll
      for (int nt = 0; nt < NT; nt++) {
        int nrow = wvN * (BN / 2) + nt * 16 + laneM;
        bf[nt] = *(const bfrag8*)&Ws[nrow * 64 + jcol];
      }
#pragma unroll
      for (int mt = 0; mt < MT; mt++)
#pragma unroll
        for (int nt = 0; nt < NT; nt++)
          acc[mt][nt] = __builtin_amdgcn_mfma_f32_16x16x32_bf16(
              bf[nt], af[mt], acc[mt][nt], 0, 0, 0);   // swapped: D[n][m]
    }
    __syncthreads();
  }

#pragma unroll
  for (int mt = 0; mt < MT; mt++) {
    int m = m0 + wvM * 32 + mt * 16 + laneM;
#pragma unroll
    for (int nt = 0; nt < NT; nt++) {
      int n = n0 + wvN * (BN / 2) + nt * 16 + kgrp * 4;
      float4 bv = *(const float4*)(bias + n);
      facc4 a = acc[mt][nt];
      float v0 = a[0] + bv.x, v1 = a[1] + bv.y, v2 = a[2] + bv.z,
            v3 = a[3] + bv.w;
      size_t off = (size_t)m * N + n;
      ushort4 o;
      if constexpr (EPI == 1) {
        o.x = f2b(gelu_fast(v0)); o.y = f2b(gelu_fast(v1));
        o.z = f2b(gelu_fast(v2)); o.w = f2b(gelu_fast(v3));
      } else {  // EPI == 4
        o.x = f2b(v0); o.y = f2b(v1); o.z = f2b(v2); o.w = f2b(v3);
      }
      *(ushort4*)(Cb + off) = o;
    }
  }
}

// ---------------- attention v2: one block per (b,h), conflict-free LDS -------
__global__ __launch_bounds__(256) void attn_kernel(
    const ushort_t* __restrict__ qkv, ushort_t* __restrict__ o) {
  int b = blockIdx.x >> 3;
  int h = blockIdx.x & 7;
  __shared__ __align__(16) float q[S][44];
  __shared__ __align__(16) float v[S][44];
  __shared__ __align__(16) float kT[DH][28];
  __shared__ __align__(16) float sc[S][28];
  int tid = threadIdx.x;
  const ushort_t* base = qkv + (size_t)b * S * (3 * D) + h * DH;

  for (int idx = tid; idx < 720; idx += 256) {
    int t = idx / 240;          // 0=q 1=k 2=v
    int r = idx % 240;
    int s = r / 10, dg = r % 10;
    ushort4 u = *(const ushort4*)(base + (size_t)s * (3 * D) + t * D + dg * 4);
    float4 f = {b2f(u.x), b2f(u.y), b2f(u.z), b2f(u.w)};
    if (t == 0) {
      *(float4*)&q[s][dg * 4] = f;
    } else if (t == 2) {
      *(float4*)&v[s][dg * 4] = f;
    } else {
      kT[dg * 4 + 0][s] = f.x;
      kT[dg * 4 + 1][s] = f.y;
      kT[dg * 4 + 2][s] = f.z;
      kT[dg * 4 + 3][s] = f.w;
    }
  }
  __syncthreads();

  if (tid < 144) {
    int i = tid / 6, jg = tid % 6;
    facc4 acc = {0.f, 0.f, 0.f, 0.f};
#pragma unroll
    for (int d = 0; d < DH; d++) {
      float qv = q[i][d];
      float4 kv = *(const float4*)&kT[d][jg * 4];
      acc[0] += qv * kv.x; acc[1] += qv * kv.y;
      acc[2] += qv * kv.z; acc[3] += qv * kv.w;
    }
    const float sca = 0.15811388300841897f;  // 1/sqrt(40)
    float4 ov = {acc[0] * sca, acc[1] * sca, acc[2] * sca, acc[3] * sca};
    *(float4*)&sc[i][jg * 4] = ov;
  }
  __syncthreads();

  if (tid < S) {
    float mx = -1e30f;
#pragma unroll
    for (int j = 0; j < S; j++) mx = fmaxf(mx, sc[tid][j]);
    float sum = 0.f;
#pragma unroll
    for (int j = 0; j < S; j++) {
      float e = __expf(sc[tid][j] - mx);
      sc[tid][j] = e;
      sum += e;
    }
    float rr = 1.0f / sum;
#pragma unroll
    for (int j = 0; j < S; j++) sc[tid][j] *= rr;
  }
  __syncthreads();

  if (tid < 240) {
    int i = tid / 10, dg = tid % 10;
    facc4 acc = {0.f, 0.f, 0.f, 0.f};
#pragma unroll
    for (int j = 0; j < S; j++) {
      float p = sc[i][j];
      float4 vv = *(const float4*)&v[j][dg * 4];
      acc[0] += p * vv.x; acc[1] += p * vv.y;
      acc[2] += p * vv.z; acc[3] += p * vv.w;
    }
    ushort4 ov;
    ov.x = f2b(acc[0]); ov.y = f2b(acc[1]);
    ov.z = f2b(acc[2]); ov.w = f2b(acc[3]);
    *(ushort4*)(o + (size_t)b * S * D + (size_t)i * D + h * DH + dg * 4) = ov;
  }
}

// ---------------- head tail: c = g@Wh2^T+bh2 ; cheb ; sigmoid ----------------
__global__ __launch_bounds__(256) void head_cheb(
    const float* __restrict__ g, const float* __restrict__ Wh2,
    const float* __restrict__ bh2, const float* __restrict__ k_norm,
    float* __restrict__ out) {
  int b = blockIdx.x;
  __shared__ float gs[D];
  __shared__ float cs[NM1];
  int tid = threadIdx.x;
  for (int i = tid; i < D; i += 256) gs[i] = g[(size_t)b * D + i];
  __syncthreads();
  if (tid < NM1) {
    const float* wr = Wh2 + (size_t)tid * D;
    float s = bh2[tid];
    for (int d = 0; d < D; d++) s += gs[d] * wr[d];
    cs[tid] = s;
  }
  __syncthreads();
  for (int t = tid; t < T_SZ; t += 256) {
    float xv = k_norm[(size_t)b * T_SZ + t];
    float tp = 1.f, tc = xv;
    float acc = cs[0] + cs[1] * xv;
#pragma unroll
    for (int n = 2; n < NM1; n++) {
      float tn = 2.f * xv * tc - tp;
      acc += cs[n] * tn;
      tp = tc;
      tc = tn;
    }
    out[(size_t)b * T_SZ + t] = 1.f / (1.f + expf(-acc));
  }
}

extern "C" void kernel_launch(void* const* d_in, const int* in_sizes, int n_in,
                              void* d_out, int out_size, void* d_ws,
                              size_t ws_size, hipStream_t stream) {
  const float* k_norm = (const float*)d_in[0];
  const float* ctx    = (const float*)d_in[1];
  const float* W_e    = (const float*)d_in[2];
  const float* b_e    = (const float*)d_in[3];
  const float* cls    = (const float*)d_in[4];
  const float* ln1_w  = (const float*)d_in[5];
  const float* ln1_b  = (const float*)d_in[6];
  const float* W_in   = (const float*)d_in[7];
  const float* b_in   = (const float*)d_in[8];
  const float* W_out  = (const float*)d_in[9];
  const float* b_out  = (const float*)d_in[10];
  const float* ln2_w  = (const float*)d_in[11];
  const float* ln2_b  = (const float*)d_in[12];
  const float* W1     = (const float*)d_in[13];
  const float* b1     = (const float*)d_in[14];
  const float* W2     = (const float*)d_in[15];
  const float* b2     = (const float*)d_in[16];
  const float* hln_w  = (const float*)d_in[17];
  const float* hln_b  = (const float*)d_in[18];
  const float* Wh1    = (const float*)d_in[19];
  const float* bh1    = (const float*)d_in[20];
  const float* Wh2    = (const float*)d_in[21];
  const float* bh2    = (const float*)d_in[22];
  float* out = (float*)d_out;

  float* x = (float*)d_ws;
  ushort_t* hbuf = (ushort_t*)(x + (size_t)M_ROWS * D);
  ushort_t* big = hbuf + (size_t)M_ROWS * D;
  ushort_t* wb_in = big + (size_t)M_ROWS * FF;
  ushort_t* wb_out = wb_in + (size_t)L_LAYERS * 3 * D * D;
  ushort_t* wb1 = wb_out + (size_t)L_LAYERS * D * D;
  ushort_t* wb2 = wb1 + (size_t)L_LAYERS * FF * D;
  ushort_t* wbh1 = wb2 + (size_t)L_LAYERS * D * FF;
  ushort_t* hcls = wbh1 + (size_t)D * D;
  float* ghead = (float*)(hcls + (size_t)B_SZ * D);
  // LN stats: sQ[6] slots (ln1 input per layer; [0] from embed, [l+1] from
  // ffn2 of layer l via atomics) | sB[5] slots (ln2 input, from outproj)
  float* sQ = ghead + (size_t)B_SZ * D;
  float* sB = sQ + (size_t)6 * M_ROWS * 2;

  // zero the atomic-accumulated stats slots (sQ[1..5] + sB[0..4]) once
  hipMemsetAsync(sQ + (size_t)M_ROWS * 2, 0,
                 (size_t)10 * M_ROWS * 2 * sizeof(float), stream);

  conv_all<<<6100, 256, 0, stream>>>(W_in, W_out, W1, W2, Wh1, wb_in);

  embed_stats<<<M_ROWS / 4, 256, 0, stream>>>(ctx, W_e, b_e, cls, x, sQ);

  for (int l = 0; l < L_LAYERS; l++) {
    float* stQ = sQ + (size_t)l * M_ROWS * 2;
    float* stB = sB + (size_t)l * M_ROWS * 2;
    float* stN = sQ + (size_t)(l + 1) * M_ROWS * 2;
    // qkv = LN1(x) @ W_in^T + b_in   (fused LN)
    gemm_ln<4, 5><<<dim3(M_ROWS / 64, (3 * D) / 160), 256, 0, stream>>>(
        x, wb_in + (size_t)l * 3 * D * D, ln1_w + l * D, ln1_b + l * D, stQ,
        b_in + (size_t)l * 3 * D, big, M_ROWS, 3 * D, D);
    attn_kernel<<<B_SZ * H, 256, 0, stream>>>(big, hbuf);
    // x += o @ W_out^T + b_out ; emit LN2 stats
    gemm_mfma<6, 64, 5><<<dim3(M_ROWS / 64, D / 160), 256, 0, stream>>>(
        hbuf, wb_out + (size_t)l * D * D, b_out + (size_t)l * D, x, x, nullptr,
        stB, M_ROWS, D, D);
    // g = gelu(LN2(x) @ W1^T + b1)   (fused LN)
    gemm_ln<1, 5><<<dim3(M_ROWS / 64, FF / 160), 256, 0, stream>>>(
        x, wb1 + (size_t)l * FF * D, ln2_w + l * D, ln2_b + l * D, stB,
        b1 + (size_t)l * FF, big, M_ROWS, FF, D);
    // x += g @ W2^T + b2 ; emit next-layer LN1 stats
    gemm_mfma<6, 64, 5><<<dim3(M_ROWS / 64, D / 160), 256, 0, stream>>>(
        big, wb2 + (size_t)l * D * FF, b2 + (size_t)l * D, x, x, nullptr, stN,
        M_ROWS, D, FF);
  }

  ln_kernel<<<B_SZ / 4, 256, 0, stream>>>(x, hln_w, hln_b, hcls, S * D, D);
  gemm_mfma<3, 64, 5><<<dim3(B_SZ / 64, D / 160), 256, 0, stream>>>(
      hcls, wbh1, bh1, nullptr, ghead, nullptr, nullptr, B_SZ, D, D);
  head_cheb<<<B_SZ, 256, 0, stream>>>(ghead, Wh2, bh2, k_norm, out);
}